// Round 1
// 1316.729 us; speedup vs baseline: 1.1854x; 1.1854x over previous
//
#include <hip/hip_runtime.h>

#define S_LEN 1024
#define NHEAD 32
#define HSZ   128
#define HIDN  4096
#define NQKV  12288
#define T_TOK 4096
// 128^-0.5 * log2(e)
#define ATT_SCALE 0.12751743f

typedef __bf16 bf16x8 __attribute__((ext_vector_type(8)));
typedef float  floatx4 __attribute__((ext_vector_type(4)));

union B8U { uint4 u; bf16x8 v; };

__device__ __forceinline__ unsigned short f2bf(float x) {
  unsigned int u = __float_as_uint(x);
  unsigned int r = (u + 0x7FFFu + ((u >> 16) & 1u)) >> 16;
  return (unsigned short)r;
}

__device__ __forceinline__ void gload_lds16(const void* g, void* l) {
  __builtin_amdgcn_global_load_lds(
      (__attribute__((address_space(1))) void*)(unsigned long long)g,
      (__attribute__((address_space(3))) void*)l, 16, 0, 0);
}

__device__ __forceinline__ bf16x8 lds_frag(const unsigned short* p) {
  return *reinterpret_cast<const bf16x8*>(p);
}

// ---------------- cast fp32 -> bf16 (contiguous) ----------------
__global__ __launch_bounds__(256) void cast_bf16_kernel(
    const float* __restrict__ in, unsigned short* __restrict__ out, int n) {
  int idx = (blockIdx.x * 256 + threadIdx.x) * 4;
  if (idx >= n) return;
  float4 f = *reinterpret_cast<const float4*>(in + idx);
  ushort4 o;
  o.x = f2bf(f.x); o.y = f2bf(f.y); o.z = f2bf(f.z); o.w = f2bf(f.w);
  *reinterpret_cast<ushort4*>(out + idx) = o;
}

// ---------------- transpose-cast: w (K,N) fp32 -> wt (N,K) bf16 ----------------
__global__ __launch_bounds__(256) void tcast_kernel(
    const float* __restrict__ w, unsigned short* __restrict__ wt, int K, int N) {
  __shared__ float tile[32][33];
  int n0 = blockIdx.x * 32, k0 = blockIdx.y * 32;
  int tx = threadIdx.x, ty = threadIdx.y;
#pragma unroll
  for (int i = 0; i < 32; i += 8)
    tile[ty + i][tx] = w[(size_t)(k0 + ty + i) * N + n0 + tx];
  __syncthreads();
#pragma unroll
  for (int i = 0; i < 32; i += 8)
    wt[(size_t)(n0 + ty + i) * K + k0 + tx] = f2bf(tile[tx][ty + i]);
}

// ---------------- GEMM 256x256 tile, BK=64, 8-phase counted-vmcnt schedule ----
// C(M,N) fp32 = A(M,K)bf16 * Bt(N,K)bf16 + bias.
// 8 waves (2M x 4N), each owns 128x64 of C as 2x2 quadrants of 64x32.
// LDS: 2 dbuf x {A,B} x 256x64 bf16 = 128 KiB, st_16x32 swizzled (bit9->bit5).
// Staging stream: 1 half-tile (128x64, 2 x global_load_lds/thread) per phase,
// 7 half-tiles ahead; slot order per K-tile {A0,B1,A1,B0} == last-read order of
// quadrant schedule (rh0ch0),(rh0ch1),(rh1ch1),(rh1ch0). vmcnt(6) at phase 4/8.
__global__ __launch_bounds__(512, 2) void gemm256(
    const unsigned short* __restrict__ A, const unsigned short* __restrict__ Bt,
    const float* __restrict__ bias, float* __restrict__ C,
    int N, int K, int NBX) {
  __shared__ __align__(16) unsigned short ldsA[2][16384];
  __shared__ __align__(16) unsigned short ldsB[2][16384];

  const int tid = threadIdx.x;
  const int lane = tid & 63, w = tid >> 6;
  const int m = lane & 15, quad = lane >> 4;
  const int wm = w >> 2, wn = w & 3;   // 2 x 4 wave grid

  // bijective XCD swizzle (nwg % 8 == 0 by construction)
  const int nwg = gridDim.x;
  const int orig = blockIdx.x;
  const int id = (orig & 7) * (nwg >> 3) + (orig >> 3);
  const int by = id / NBX, bx = id - by * NBX;
  const int tM = by << 8, tN = bx << 8;
  const int NT = K >> 6;

  const unsigned short* pA = A + (size_t)tM * K;
  const unsigned short* pB = Bt + (size_t)tN * K;

  // Per-thread inverse-swizzled global source offset for linear LDS dest
  // o = tid*16 bytes within a 16KB half (128 rows x 64 cols bf16, 16x32 subtiles)
  size_t goff0;
  {
    int o = tid * 16;
    int blk = o >> 10;                               // 16x32 subtile index
    int r = (o >> 6) & 15;                           // row within subtile
    int cB = (o & 63) ^ (((r >> 3) & 1) << 5);       // inverse swizzle (involution)
    goff0 = (size_t)((blk >> 1) * 16 + r) * K + ((blk & 1) << 5) + (cB >> 1);
  }
  const size_t goff1 = goff0 + (size_t)64 * K;       // second 8KB chunk = rows +64
  const int ldst0 = tid * 16;

  // swizzled ds_read inner offset (constant per thread)
  const int innerOff = (m << 6) + (((quad * 8) ^ (((m >> 3) & 1) << 4)) << 1);

  floatx4 acc[2][2][4][2] = {};

  auto STAGE = [&](int s) {
    if (s < 4 * NT) {
      const int tt = s >> 2, slot = s & 3;
      const int buf = tt & 1;
      const int half = (slot == 1 || slot == 2) ? 1 : 0;  // {A0,B1,A1,B0}
      const unsigned short* g =
          ((slot & 1) ? pB : pA) + (size_t)(half << 7) * K + (tt << 6);
      char* l = (char*)((slot & 1) ? ldsB[buf] : ldsA[buf]) + (half << 14);
      gload_lds16(g + goff0, l + ldst0);
      gload_lds16(g + goff1, l + ldst0 + 8192);
    }
  };

  auto FRAG = [&](const unsigned short* tile, int br, int kk) -> bf16x8 {
    return *reinterpret_cast<const bf16x8*>(
        (const char*)tile + ((((br << 1) + kk) << 10) + innerOff));
  };

  auto MQ = [&](floatx4 (&ac)[4][2], bf16x8 (&aa)[4][2], bf16x8 (&bb)[2][2]) {
#pragma unroll
    for (int kk = 0; kk < 2; ++kk)
#pragma unroll
      for (int i = 0; i < 4; ++i)
#pragma unroll
        for (int j = 0; j < 2; ++j)
          ac[i][j] = __builtin_amdgcn_mfma_f32_16x16x32_bf16(
              aa[i][kk], bb[j][kk], ac[i][j], 0, 0, 0);
  };

  // prologue: 7 half-tiles in flight; need first K-tile (h0..h3) landed
#pragma unroll
  for (int s = 0; s < 7; ++s) STAGE(s);
  asm volatile("s_waitcnt vmcnt(6)" ::: "memory");
  __builtin_amdgcn_s_barrier();
  asm volatile("" ::: "memory");

#pragma unroll 2
  for (int t = 0; t < NT; ++t) {
    const unsigned short* lA = ldsA[t & 1];
    const unsigned short* lB = ldsB[t & 1];
    const int P = t << 2;
    bf16x8 a[4][2], b0[2][2], b1[2][2];

    // ---- phase 0: quadrant (rh0, ch0) — 12 ds_reads, last read of A-half0
#pragma unroll
    for (int i = 0; i < 4; ++i) {
      a[i][0] = FRAG(lA, wm * 4 + i, 0);
      a[i][1] = FRAG(lA, wm * 4 + i, 1);
    }
#pragma unroll
    for (int j = 0; j < 2; ++j) {
      b0[j][0] = FRAG(lB, wn * 2 + j, 0);
      b0[j][1] = FRAG(lB, wn * 2 + j, 1);
    }
    STAGE(P + 7);                      // tile t+1, B-half0
    __builtin_amdgcn_s_barrier();
    asm volatile("s_waitcnt lgkmcnt(0)" ::: "memory");
    __builtin_amdgcn_s_setprio(1);
    MQ(acc[0][0], a, b0);
    __builtin_amdgcn_s_setprio(0);
    __builtin_amdgcn_s_barrier();

    // ---- phase 1: quadrant (rh0, ch1) — 4 ds_reads, last read of B-half1
#pragma unroll
    for (int j = 0; j < 2; ++j) {
      b1[j][0] = FRAG(lB, wn * 2 + 8 + j, 0);
      b1[j][1] = FRAG(lB, wn * 2 + 8 + j, 1);
    }
    STAGE(P + 8);                      // tile t+2, A-half0 (region freed at p0)
    __builtin_amdgcn_s_barrier();
    asm volatile("s_waitcnt lgkmcnt(0)" ::: "memory");
    __builtin_amdgcn_s_setprio(1);
    MQ(acc[0][1], a, b1);
    __builtin_amdgcn_s_setprio(0);
    __builtin_amdgcn_s_barrier();

    // ---- phase 2: quadrant (rh1, ch1) — 8 ds_reads, last read of A-half1
#pragma unroll
    for (int i = 0; i < 4; ++i) {
      a[i][0] = FRAG(lA, wm * 4 + 8 + i, 0);
      a[i][1] = FRAG(lA, wm * 4 + 8 + i, 1);
    }
    STAGE(P + 9);                      // tile t+2, B-half1 (freed at p1)
    __builtin_amdgcn_s_barrier();
    asm volatile("s_waitcnt lgkmcnt(0)" ::: "memory");
    __builtin_amdgcn_s_setprio(1);
    MQ(acc[1][1], a, b1);
    __builtin_amdgcn_s_setprio(0);
    __builtin_amdgcn_s_barrier();

    // ---- phase 3: quadrant (rh1, ch0) — 4 ds_reads, last read of B-half0
#pragma unroll
    for (int j = 0; j < 2; ++j) {
      b0[j][0] = FRAG(lB, wn * 2 + j, 0);
      b0[j][1] = FRAG(lB, wn * 2 + j, 1);
    }
    STAGE(P + 10);                     // tile t+2, A-half1 (freed at p2)
    __builtin_amdgcn_s_barrier();
    asm volatile("s_waitcnt lgkmcnt(0)" ::: "memory");
    __builtin_amdgcn_s_setprio(1);
    MQ(acc[1][0], a, b0);
    __builtin_amdgcn_s_setprio(0);
    // K-tile boundary: everything except the newest 3 half-tiles must land
    if (t + 2 < NT) asm volatile("s_waitcnt vmcnt(6)" ::: "memory");
    else            asm volatile("s_waitcnt vmcnt(0)" ::: "memory");
    __builtin_amdgcn_s_barrier();
    asm volatile("" ::: "memory");
  }

  // ---- epilogue
#pragma unroll
  for (int rh = 0; rh < 2; ++rh)
#pragma unroll
    for (int ch = 0; ch < 2; ++ch)
#pragma unroll
      for (int i = 0; i < 4; ++i)
#pragma unroll
        for (int j = 0; j < 2; ++j) {
          const int row = tM + wm * 64 + rh * 128 + i * 16 + quad * 4;
          const int col = tN + wn * 32 + ch * 128 + j * 16 + m;
          const float bb = bias ? bias[col] : 0.0f;
          float* cp = C + (size_t)row * N + col;
#pragma unroll
          for (int rr = 0; rr < 4; ++rr)
            cp[(size_t)rr * N] = acc[rh][ch][i][j][rr] + bb;
        }
}

// ---------------- rope + kv scatter ----------------
__global__ __launch_bounds__(256) void rope_kernel(
    const float* __restrict__ qkv, const float* __restrict__ cosb,
    const float* __restrict__ sinb, const int* __restrict__ slots,
    unsigned short* __restrict__ Qb, unsigned short* __restrict__ Kb,
    float* __restrict__ KvK, float* __restrict__ KvV) {
  const int t = blockIdx.x, tid = threadIdx.x;
  const size_t base = (size_t)t * NQKV;
  const int slot = slots[t];
  const size_t obase = (size_t)t * 4096;
  const size_t cbase = (size_t)slot * 4096;
  for (int idx = tid; idx < NHEAD * 32; idx += 256) {
    int hh = idx >> 5, r = idx & 31;
    float c = cosb[t * 32 + r], sn = sinb[t * 32 + r];
    int d0 = hh * 128 + r;
    float q1 = qkv[base + d0], q2 = qkv[base + d0 + 32];
    float k1 = qkv[base + 4096 + d0], k2 = qkv[base + 4096 + d0 + 32];
    float qr1 = q1 * c - q2 * sn, qr2 = q2 * c + q1 * sn;
    float kr1 = k1 * c - k2 * sn, kr2 = k2 * c + k1 * sn;
    Qb[obase + d0]      = f2bf(qr1 * ATT_SCALE);
    Qb[obase + d0 + 32] = f2bf(qr2 * ATT_SCALE);
    Kb[obase + d0]      = f2bf(kr1);
    Kb[obase + d0 + 32] = f2bf(kr2);
    KvK[cbase + d0] = kr1; KvK[cbase + d0 + 32] = kr2;
  }
  for (int idx = tid; idx < NHEAD * 64; idx += 256) {
    int hh = idx >> 6, p = idx & 63;
    int d = hh * 128 + 64 + p;
    float q = qkv[base + d], k = qkv[base + 4096 + d];
    Qb[obase + d] = f2bf(q * ATT_SCALE);
    Kb[obase + d] = f2bf(k);
    KvK[cbase + d] = k;
  }
  for (int idx = tid; idx < NHEAD * 128; idx += 256)
    KvV[cbase + idx] = qkv[base + 8192 + idx];
}

// ---------------- V transpose: qkv v-part (b,s,h,d) fp32 -> Vt (bh, d, s) bf16 ----------------
__global__ __launch_bounds__(256) void vtrans_kernel(
    const float* __restrict__ qkv, unsigned short* __restrict__ vt) {
  __shared__ float tile[32][33];
  int s0 = blockIdx.x * 32, d0 = blockIdx.y * 32, bh = blockIdx.z;
  int b = bh >> 5, h = bh & 31;
  int tx = threadIdx.x, ty = threadIdx.y;
#pragma unroll
  for (int i = 0; i < 32; i += 8)
    tile[ty + i][tx] =
        qkv[(size_t)(b * S_LEN + s0 + ty + i) * NQKV + 8192 + h * 128 + d0 + tx];
  __syncthreads();
#pragma unroll
  for (int i = 0; i < 32; i += 8)
    vt[(size_t)(bh * 128 + d0 + ty + i) * S_LEN + s0 + tx] = f2bf(tile[tx][ty + i]);
}

// ---------------- MFMA flash attention ----------------
__global__ __launch_bounds__(256) void attn_kernel(
    const unsigned short* __restrict__ Q, const unsigned short* __restrict__ Kb,
    const unsigned short* __restrict__ Vt, unsigned short* __restrict__ Ob) {
  __shared__ __align__(16) unsigned short Ks[32][136];
  __shared__ __align__(16) unsigned short Vs[128][40];
  __shared__ __align__(16) unsigned short Pb[4][16][40];

  const int tid = threadIdx.x;
  const int w = tid >> 6, lane = tid & 63;
  const int m = lane & 15, quad = lane >> 4;
  const int qb = blockIdx.x, bh = blockIdx.y;
  const int b = bh >> 5, h = bh & 31;

  const int rowA = qb * 64 + w * 16 + m;
  const size_t qoff = ((size_t)(b * S_LEN + rowA)) * 4096 + h * 128;

  bf16x8 qf[4];
#pragma unroll
  for (int kc = 0; kc < 4; ++kc) {
    B8U t; t.u = *reinterpret_cast<const uint4*>(Q + qoff + kc * 32 + quad * 8);
    qf[kc] = t.v;
  }

  floatx4 O[8] = {};
  float m_run[4], l_run[4], alpha[4];
#pragma unroll
  for (int r = 0; r < 4; ++r) { m_run[r] = -3e38f; l_run[r] = 0.0f; }

  const int kend = qb * 64 + 63;
  for (int k0 = 0; k0 <= kend; k0 += 32) {
#pragma unroll
    for (int it = 0; it < 2; ++it) {
      int c = tid + it * 256;
      int key = c >> 4, d0 = (c & 15) * 8;
      uint4 val = *reinterpret_cast<const uint4*>(
          Kb + ((size_t)(b * S_LEN + k0 + key)) * 4096 + h * 128 + d0);
      *reinterpret_cast<uint4*>(&Ks[key][d0]) = val;
    }
#pragma unroll
    for (int it = 0; it < 2; ++it) {
      int c = tid + it * 256;
      int d = c >> 2, kk = (c & 3) * 8;
      uint4 val = *reinterpret_cast<const uint4*>(
          Vt + ((size_t)bh * 128 + d) * S_LEN + k0 + kk);
      *reinterpret_cast<uint4*>(&Vs[d][kk]) = val;
    }
    __syncthreads();

    floatx4 s[2];
#pragma unroll
    for (int t16 = 0; t16 < 2; ++t16) {
      floatx4 a = {};
#pragma unroll
      for (int kc = 0; kc < 4; ++kc) {
        bf16x8 kf = lds_frag(&Ks[t16 * 16 + m][kc * 32 + quad * 8]);
        a = __builtin_amdgcn_mfma_f32_16x16x32_bf16(qf[kc], kf, a, 0, 0, 0);
      }
      s[t16] = a;
    }

#pragma unroll
    for (int r = 0; r < 4; ++r) {
      int rowD = qb * 64 + w * 16 + quad * 4 + r;
      float s0 = s[0][r]; if (k0 + m > rowD)      s0 = -3e38f;
      float s1 = s[1][r]; if (k0 + 16 + m > rowD) s1 = -3e38f;
      float mx = fmaxf(s0, s1);
#pragma unroll
      for (int off = 8; off > 0; off >>= 1) mx = fmaxf(mx, __shfl_xor(mx, off));
      float mn = fmaxf(m_run[r], mx);
      float al = exp2f(m_run[r] - mn);
      float p0 = exp2f(s0 - mn), p1 = exp2f(s1 - mn);
      float rs = p0 + p1;
#pragma unroll
      for (int off = 8; off > 0; off >>= 1) rs += __shfl_xor(rs, off);
      l_run[r] = l_run[r] * al + rs;
      m_run[r] = mn; alpha[r] = al;
      Pb[w][quad * 4 + r][m]      = f2bf(p0);
      Pb[w][quad * 4 + r][16 + m] = f2bf(p1);
    }

#pragma unroll
    for (int nd = 0; nd < 8; ++nd)
#pragma unroll
      for (int r = 0; r < 4; ++r) O[nd][r] *= alpha[r];

    bf16x8 pf = lds_frag(&Pb[w][m][quad * 8]);
#pragma unroll
    for (int nd = 0; nd < 8; ++nd) {
      bf16x8 vf = lds_frag(&Vs[nd * 16 + m][quad * 8]);
      O[nd] = __builtin_amdgcn_mfma_f32_16x16x32_bf16(pf, vf, O[nd], 0, 0, 0);
    }
    __syncthreads();
  }

#pragma unroll
  for (int r = 0; r < 4; ++r) {
    int rowD = qb * 64 + w * 16 + quad * 4 + r;
    float inv = 1.0f / l_run[r];
    size_t obase = ((size_t)(b * S_LEN + rowD)) * 4096 + h * 128;
#pragma unroll
    for (int nd = 0; nd < 8; ++nd)
      Ob[obase + nd * 16 + m] = f2bf(O[nd][r] * inv);
  }
}

// ---------------- launch ----------------
extern "C" void kernel_launch(void* const* d_in, const int* in_sizes, int n_in,
                              void* d_out, int out_size, void* d_ws, size_t ws_size,
                              hipStream_t stream) {
  const float* hidden  = (const float*)d_in[0];
  const float* cosb    = (const float*)d_in[1];
  const float* sinb    = (const float*)d_in[2];
  const float* w_qkv   = (const float*)d_in[3];
  const float* b_qkv   = (const float*)d_in[4];
  const float* w_dense = (const float*)d_in[5];
  const int*   slots   = (const int*)d_in[8];

  float* out = (float*)d_out;
  float* kvk = out + 16777216;
  float* kvv = out + 33554432;

  char* ws = (char*)d_ws;
  unsigned short* bfA = (unsigned short*)ws;                    // 33.5 MB (hidden bf16, later attn bf16)
  unsigned short* Wt  = (unsigned short*)(ws + 33554432);       // 100.7 MB (weights^T bf16, reused)
  float*          qkv = (float*)(ws + 134217728);               // 201.3 MB
  unsigned short* Qb  = (unsigned short*)(ws + 335544320);      // 33.5 MB
  unsigned short* Kb  = (unsigned short*)(ws + 369098752);      // 33.5 MB
  unsigned short* Vt  = (unsigned short*)(ws + 402653184);      // 33.5 MB

  cast_bf16_kernel<<<16384, 256, 0, stream>>>(hidden, bfA, T_TOK * HIDN);
  tcast_kernel<<<dim3(NQKV / 32, HIDN / 32), dim3(32, 8), 0, stream>>>(w_qkv, Wt, HIDN, NQKV);
  // QKV GEMM: 16 x 48 tiles of 256x256, nwg=768 (divisible by 8)
  gemm256<<<dim3((T_TOK / 256) * (NQKV / 256)), 512, 0, stream>>>(
      bfA, Wt, b_qkv, qkv, NQKV, HIDN, NQKV / 256);
  rope_kernel<<<T_TOK, 256, 0, stream>>>(qkv, cosb, sinb, slots, Qb, Kb, kvk, kvv);
  vtrans_kernel<<<dim3(S_LEN / 32, HSZ / 32, 128), dim3(32, 8), 0, stream>>>(qkv, Vt);
  attn_kernel<<<dim3(S_LEN / 64, 128), 256, 0, stream>>>(Qb, Kb, Vt, bfA);
  tcast_kernel<<<dim3(HIDN / 32, HIDN / 32), dim3(32, 8), 0, stream>>>(w_dense, Wt, HIDN, HIDN);
  // dense GEMM: 16 x 16 tiles, nwg=256
  gemm256<<<dim3((T_TOK / 256) * (HIDN / 256)), 512, 0, stream>>>(
      bfA, Wt, nullptr, out, HIDN, HIDN, HIDN / 256);
}